// Round 2
// baseline (1508.102 us; speedup 1.0000x reference)
//
#include <hip/hip_runtime.h>

typedef __attribute__((ext_vector_type(8))) short short8;
typedef __attribute__((ext_vector_type(4))) float f32x4;

#define BB 32
#define LL 2048
#define HH 256
#define MTOT (BB*LL)          // 65536 rows
#define KK 1536               // 6 chunks * 256
#define HSIZE (MTOT*HH)       // 16777216 elements per output tensor

__device__ __forceinline__ unsigned short f2bf(float f){
    unsigned u = __builtin_bit_cast(unsigned, f);
    u += 0x7FFFu + ((u >> 16) & 1u);          // round-to-nearest-even
    return (unsigned short)(u >> 16);
}
__device__ __forceinline__ unsigned pk2(float lo, float hi){
    return (unsigned)f2bf(lo) | ((unsigned)f2bf(hi) << 16);
}
__device__ __forceinline__ float sigm(float v){
    return 1.0f / (1.0f + __expf(-v));
}
__device__ __forceinline__ float ftanh(float v){
    v = fminf(fmaxf(v, -30.0f), 30.0f);
    float e = __expf(2.0f * v);
    return (e - 1.0f) / (e + 1.0f);
}

// ---------------------------------------------------------------------------
// h_t f32 -> bf16 (8 elements per thread, fully coalesced)
// ---------------------------------------------------------------------------
__global__ __launch_bounds__(256) void conv_bf16(const float* __restrict__ src,
                                                 unsigned short* __restrict__ dst){
    int idx = blockIdx.x * 256 + threadIdx.x;     // 0 .. 2097151
    const float4* s = (const float4*)src;
    float4 v0 = s[2 * idx], v1 = s[2 * idx + 1];
    uint4 w;
    w.x = pk2(v0.x, v0.y); w.y = pk2(v0.z, v0.w);
    w.z = pk2(v1.x, v1.y); w.w = pk2(v1.z, v1.w);
    ((uint4*)dst)[idx] = w;
}

// ---------------------------------------------------------------------------
// Ws [6][1536][256] f32  ->  Bt [1536][1536] bf16, Bt[g*256+h][k] = Ws[g][k][h]
// ---------------------------------------------------------------------------
__global__ __launch_bounds__(256) void prep_bt(const float* __restrict__ Ws,
                                               unsigned short* __restrict__ Bt){
    __shared__ float tile[64][65];
    int bid = blockIdx.x;
    int kb = bid % 24; int tmp = bid / 24; int hb = tmp & 3; int g = tmp >> 2;
    int t = threadIdx.x;
    const float* src = Ws + (size_t)g * (KK * HH) + (size_t)(kb * 64) * HH + hb * 64;
    #pragma unroll
    for (int it = 0; it < 16; ++it){
        int e = it * 256 + t; int kk = e >> 6, hh = e & 63;
        tile[kk][hh] = src[(size_t)kk * HH + hh];
    }
    __syncthreads();
    unsigned short* dst = Bt + (size_t)(g * 256 + hb * 64) * KK + kb * 64;
    #pragma unroll
    for (int it = 0; it < 16; ++it){
        int e = it * 256 + t; int hh = e >> 6, kk = e & 63;
        dst[(size_t)hh * KK + kk] = f2bf(tile[kk][hh]);
    }
}

// ---------------------------------------------------------------------------
// Fused GEMM + sLSTM epilogue. ALL-REGISTER: no LDS, no barriers.
// Block 512 thr = 8 waves: rg (0/1) x ht (0..3). Wave = 64 rows x (6g x 16h).
// A fragments loaded straight from global (bf16 h_t for chunks 0-2 incl.
// sequence shifts; f32 x/h_slot/h_intent repacked in-reg for chunks 3-5).
// B fragments loaded straight from pre-transposed Bt (bf16, L2-resident).
// ---------------------------------------------------------------------------
__global__ __launch_bounds__(512, 2) void slstm_fused(
    const unsigned short* __restrict__ hb,     // h_t in bf16 [65536][256]
    const float* __restrict__ x, const float* __restrict__ h_slot,
    const float* __restrict__ h_intent, const float* __restrict__ c_t,
    const float* __restrict__ bs, const unsigned short* __restrict__ Bt,
    float* __restrict__ out)
{
    const int t    = threadIdx.x;
    const int wv   = t >> 6,  ln  = t & 63;
    const int rg   = wv >> 2, ht  = wv & 3;
    const int quad = ln >> 4, l16 = ln & 15;

    const int h_chunk = blockIdx.x & 3;        // h fastest -> per-XCD B locality
    const int m_block = blockIdx.x >> 2;
    const int h0      = h_chunk * 64;

    long row[4]; int ls[4];
    #pragma unroll
    for (int mt = 0; mt < 4; ++mt){
        row[mt] = (long)m_block * 128 + rg * 64 + mt * 16 + l16;
        ls[mt]  = (int)(row[mt] & (LL - 1));
    }

    // B fragment base: lane's column row in Bt, at its k-octet
    const unsigned short* bp = Bt + (size_t)(h0 + ht * 16 + l16) * KK + quad * 8;

    f32x4 acc[4][6] = {};                      // [m-tile][gate]

    // ---- chunks 0..2: h_t (bf16) with shifts {0,-1,+1} ----
    #pragma unroll
    for (int c = 0; c < 3; ++c){
        const int sh = (c == 0) ? 0 : ((c == 1) ? -1 : 1);
        const unsigned short* ap[4]; bool va[4];
        #pragma unroll
        for (int mt = 0; mt < 4; ++mt){
            va[mt] = ((unsigned)(ls[mt] + sh) < (unsigned)LL);
            long r2 = va[mt] ? (row[mt] + sh) : row[mt];     // safe addr when OOB
            ap[mt] = hb + r2 * HH + quad * 8;
        }
        #pragma unroll 2
        for (int k8 = 0; k8 < 8; ++k8){
            const int kk = k8 * 32;
            short8 a[4];
            #pragma unroll
            for (int mt = 0; mt < 4; ++mt){
                short8 v = *(const short8*)(ap[mt] + kk);
                short8 z = {};
                a[mt] = va[mt] ? v : z;
            }
            #pragma unroll
            for (int g = 0; g < 6; ++g){
                short8 b = *(const short8*)(bp + (size_t)g * HH * KK + c * HH + kk);
                #pragma unroll
                for (int mt = 0; mt < 4; ++mt)
                    acc[mt][g] = __builtin_amdgcn_mfma_f32_16x16x32_bf16(a[mt], b, acc[mt][g], 0, 0, 0);
            }
        }
    }

    // ---- chunks 3..5: x, h_slot, h_intent (f32, repack in-reg) ----
    const float* fsrc[3] = {x, h_slot, h_intent};
    #pragma unroll
    for (int c3 = 0; c3 < 3; ++c3){
        const float* ap[4];
        #pragma unroll
        for (int mt = 0; mt < 4; ++mt)
            ap[mt] = fsrc[c3] + row[mt] * HH + quad * 8;
        #pragma unroll 2
        for (int k8 = 0; k8 < 8; ++k8){
            const int kk = k8 * 32;
            short8 a[4];
            #pragma unroll
            for (int mt = 0; mt < 4; ++mt){
                float4 v0 = *(const float4*)(ap[mt] + kk);
                float4 v1 = *(const float4*)(ap[mt] + kk + 4);
                union { uint4 u; short8 s; } cv;
                cv.u.x = pk2(v0.x, v0.y); cv.u.y = pk2(v0.z, v0.w);
                cv.u.z = pk2(v1.x, v1.y); cv.u.w = pk2(v1.z, v1.w);
                a[mt] = cv.s;
            }
            #pragma unroll
            for (int g = 0; g < 6; ++g){
                short8 b = *(const short8*)(bp + (size_t)g * HH * KK + (3 + c3) * HH + kk);
                #pragma unroll
                for (int mt = 0; mt < 4; ++mt)
                    acc[mt][g] = __builtin_amdgcn_mfma_f32_16x16x32_bf16(a[mt], b, acc[mt][g], 0, 0, 0);
            }
        }
    }

    // ---- epilogue: all 6 gates for (row,h) live in this lane ----
    const int h = h0 + ht * 16 + l16;
    float bias[6];
    #pragma unroll
    for (int g = 0; g < 6; ++g) bias[g] = bs[g * HH + h];

    #pragma unroll
    for (int mt = 0; mt < 4; ++mt){
        #pragma unroll
        for (int r = 0; r < 4; ++r){
            long orow = (long)m_block * 128 + rg * 64 + mt * 16 + quad * 4 + r;
            int  lsq  = (int)(orow & (LL - 1));
            float gi = sigm(acc[mt][0][r] + bias[0]);
            float go = sigm(acc[mt][1][r] + bias[1]);
            float gf = sigm(acc[mt][2][r] + bias[2]);
            float gl = sigm(acc[mt][3][r] + bias[3]);
            float gr = sigm(acc[mt][4][r] + bias[4]);
            float gu = ftanh(acc[mt][5][r] + bias[5]);
            float ei = __expf(gi), ef = __expf(gf), el = __expf(gl), er = __expf(gr);
            float inv = 1.0f / (ei + ef + el + er);
            float cm  = c_t[orow * HH + h];
            float clv = (lsq > 0)      ? c_t[(orow - 1) * HH + h] : 0.0f;
            float crv = (lsq < LL - 1) ? c_t[(orow + 1) * HH + h] : 0.0f;
            float cn  = (ef * cm + el * clv + er * crv + ei * gu) * inv;
            float hn  = go * ftanh(cn);
            out[orow * HH + h]         = hn;
            out[HSIZE + orow * HH + h] = cn;
        }
    }
}

extern "C" void kernel_launch(void* const* d_in, const int* in_sizes, int n_in,
                              void* d_out, int out_size, void* d_ws, size_t ws_size,
                              hipStream_t stream){
    const float* h_t      = (const float*)d_in[0];
    const float* x        = (const float*)d_in[1];
    const float* h_slot   = (const float*)d_in[2];
    const float* h_intent = (const float*)d_in[3];
    const float* c_t      = (const float*)d_in[4];
    const float* Ws       = (const float*)d_in[5];
    const float* bs       = (const float*)d_in[6];

    unsigned short* Bt = (unsigned short*)d_ws;                       // 4.72 MB
    unsigned short* hb = (unsigned short*)((char*)d_ws + (size_t)KK * KK * 2); // 33.5 MB

    conv_bf16<<<8192, 256, 0, stream>>>(h_t, hb);
    prep_bt<<<576, 256, 0, stream>>>(Ws, Bt);
    slstm_fused<<<2048, 512, 0, stream>>>(hb, x, h_slot, h_intent, c_t, bs, Bt, (float*)d_out);
}